// Round 2
// baseline (190.017 us; speedup 1.0000x reference)
//
#include <hip/hip_runtime.h>

// Carry-save adder over {0,1}-valued floats == exact 16-bit integer circuit.
//
// Reference semantics (verified against the JAX code):
//   in0 = bits(x[:,0]); tc = bits(x[:,1]); cnt = 0
//   for i in 2..L-1:   (keep = mask[i] > 0)
//     s = in0 ^ xi ^ tc;  c = maj(in0, xi, tc)
//     if keep: cnt += bit15(c); in0 = s; tc = (c << 1) & 0xFFFF
//   sum = in0 + tc   (ripple-carry adder == integer add)
//   output bits = sum & 0xFFFF;  carry = cnt + bit16(sum)

__device__ __forceinline__ unsigned pack16(const float4* __restrict__ p) {
    // 16 floats, each exactly 0.0f or 1.0f -> 16-bit mask.
    // FMA dot with powers of two is exact (result < 2^16 < 2^24).
    float4 f0 = p[0], f1 = p[1], f2 = p[2], f3 = p[3];
    float acc = f0.x;
    acc = fmaf(f0.y,     2.f, acc);
    acc = fmaf(f0.z,     4.f, acc);
    acc = fmaf(f0.w,     8.f, acc);
    acc = fmaf(f1.x,    16.f, acc);
    acc = fmaf(f1.y,    32.f, acc);
    acc = fmaf(f1.z,    64.f, acc);
    acc = fmaf(f1.w,   128.f, acc);
    acc = fmaf(f2.x,   256.f, acc);
    acc = fmaf(f2.y,   512.f, acc);
    acc = fmaf(f2.z,  1024.f, acc);
    acc = fmaf(f2.w,  2048.f, acc);
    acc = fmaf(f3.x,  4096.f, acc);
    acc = fmaf(f3.y,  8192.f, acc);
    acc = fmaf(f3.z, 16384.f, acc);
    acc = fmaf(f3.w, 32768.f, acc);
    return (unsigned)acc;
}

// ---------------- Kernel 1: pack x into uint16 bitmasks ----------------
// Thread t handles slice t (row r = t/L, step i = t%L): reads its own 64 B
// cache line (4x float4), writes packed[t] (coalesced 2 B/lane).
__global__ __launch_bounds__(256) void csa_pack(const float* __restrict__ x,
                                                unsigned short* __restrict__ packed,
                                                int n_slices) {
    int t = blockIdx.x * 256 + threadIdx.x;
    if (t >= n_slices) return;
    const float4* p = reinterpret_cast<const float4*>(x) + (size_t)t * 4;
    packed[t] = (unsigned short)pack16(p);
}

// ---------------- Kernel 2: per-row bit scan (L == 64 specialized) -----
__global__ __launch_bounds__(256) void csa_scan64(const unsigned short* __restrict__ packed,
                                                  const int* __restrict__ mask,
                                                  float* __restrict__ out,
                                                  float* __restrict__ carry_out,
                                                  int B) {
    int r = blockIdx.x * 256 + threadIdx.x;

    // One mask load per thread + one ballot -> full 64-bit keep mask in a reg.
    // (B is a multiple of 256, so all 64 lanes of every wave are active.)
    unsigned long long keepmask = __ballot(mask[threadIdx.x & 63] > 0);

    if (r >= B) return;

    // 64 uint16 = 128 B per row, L2/L3-resident after kernel 1.
    const uint4* p = reinterpret_cast<const uint4*>(packed + (size_t)r * 64);
    unsigned w[32];
#pragma unroll
    for (int k = 0; k < 8; ++k) {
        uint4 v = p[k];
        w[4 * k + 0] = v.x; w[4 * k + 1] = v.y;
        w[4 * k + 2] = v.z; w[4 * k + 3] = v.w;
    }

    unsigned in0 = w[0] & 0xFFFFu;
    unsigned tc  = (w[0] >> 16) & 0xFFFFu;
    unsigned cnt = 0;

#pragma unroll
    for (int i = 2; i < 64; ++i) {          // i compile-time -> w[] stays in regs
        unsigned xi = (w[i >> 1] >> ((i & 1) * 16)) & 0xFFFFu;
        unsigned s  = in0 ^ xi ^ tc;
        unsigned c  = (in0 & xi) | (tc & (in0 | xi));   // majority
        if ((keepmask >> i) & 1ull) {       // wave-uniform branch
            cnt += (c >> 15) & 1u;
            in0 = s;
            tc  = (c << 1) & 0xFFFFu;
        }
    }

    unsigned sum = in0 + tc;                // ripple-carry adder == int add
    cnt += (sum >> 16) & 1u;

    float4* orow = reinterpret_cast<float4*>(out + (size_t)r * 16);
#pragma unroll
    for (int q = 0; q < 4; ++q) {
        float4 o;
        o.x = (float)((sum >> (q * 4 + 0)) & 1u);
        o.y = (float)((sum >> (q * 4 + 1)) & 1u);
        o.z = (float)((sum >> (q * 4 + 2)) & 1u);
        o.w = (float)((sum >> (q * 4 + 3)) & 1u);
        orow[q] = o;
    }
    carry_out[r] = (float)cnt;
}

// ---------------- Fallback: fused thread-per-row, general L ------------
__global__ __launch_bounds__(256) void csa_fused(const float* __restrict__ x,
                                                 const int* __restrict__ mask,
                                                 float* __restrict__ out,
                                                 float* __restrict__ carry_out,
                                                 int B, int L) {
    int r = blockIdx.x * 256 + threadIdx.x;
    if (r >= B) return;
    const float4* row = reinterpret_cast<const float4*>(x) + (size_t)r * L * 4;

    unsigned in0 = pack16(row);
    unsigned tc  = pack16(row + 4);
    unsigned cnt = 0;
    for (int i = 2; i < L; ++i) {
        unsigned xi = pack16(row + (size_t)i * 4);
        unsigned s  = in0 ^ xi ^ tc;
        unsigned c  = (in0 & xi) | (tc & (in0 | xi));
        if (mask[i] > 0) {
            cnt += (c >> 15) & 1u;
            in0 = s;
            tc  = (c << 1) & 0xFFFFu;
        }
    }
    unsigned sum = in0 + tc;
    cnt += (sum >> 16) & 1u;

    float4* orow = reinterpret_cast<float4*>(out + (size_t)r * 16);
#pragma unroll
    for (int q = 0; q < 4; ++q) {
        float4 o;
        o.x = (float)((sum >> (q * 4 + 0)) & 1u);
        o.y = (float)((sum >> (q * 4 + 1)) & 1u);
        o.z = (float)((sum >> (q * 4 + 2)) & 1u);
        o.w = (float)((sum >> (q * 4 + 3)) & 1u);
        orow[q] = o;
    }
    carry_out[r] = (float)cnt;
}

extern "C" void kernel_launch(void* const* d_in, const int* in_sizes, int n_in,
                              void* d_out, int out_size, void* d_ws, size_t ws_size,
                              hipStream_t stream) {
    const float* x    = (const float*)d_in[0];
    const int*   mask = (const int*)d_in[1];
    float*       out  = (float*)d_out;

    const int L = in_sizes[1];                 // 64
    const int B = in_sizes[0] / (L * 16);      // 32768 (NBITS = 16)
    float* carry_out = out + (size_t)B * 16;

    const size_t n_slices = (size_t)B * L;
    const size_t need     = n_slices * sizeof(unsigned short);

    if (L == 64 && (B % 256) == 0 && ws_size >= need) {
        unsigned short* packed = (unsigned short*)d_ws;
        csa_pack<<<dim3((unsigned)((n_slices + 255) / 256)), dim3(256), 0, stream>>>(
            x, packed, (int)n_slices);
        csa_scan64<<<dim3((unsigned)((B + 255) / 256)), dim3(256), 0, stream>>>(
            packed, mask, out, carry_out, B);
    } else {
        csa_fused<<<dim3((unsigned)((B + 255) / 256)), dim3(256), 0, stream>>>(
            x, mask, out, carry_out, B, L);
    }
}